// Round 1
// baseline (182.154 us; speedup 1.0000x reference)
//
#include <hip/hip_runtime.h>
#include <math.h>

#define EPS 1e-12f

// Kernel 1: per-row reciprocal L2 norm. One 64-lane wave per row (D=128 -> float2/lane).
__global__ void __launch_bounds__(256) rnorm_kernel(const float* __restrict__ h,
                                                    float* __restrict__ rnorm,
                                                    int N) {
    int wave = (blockIdx.x * blockDim.x + threadIdx.x) >> 6;
    int lane = threadIdx.x & 63;
    if (wave >= N) return;
    const float2* row = (const float2*)(h + (size_t)wave * 128);
    float2 v = row[lane];
    float s = v.x * v.x + v.y * v.y;
    // full 64-lane xor-shuffle reduction
    #pragma unroll
    for (int off = 32; off > 0; off >>= 1)
        s += __shfl_xor(s, off, 64);
    if (lane == 0) {
        float n = sqrtf(s);
        rnorm[wave] = 1.0f / fmaxf(n, EPS);
    }
}

// Kernel 2: per-edge dot. 32 lanes per edge, each lane one float4 of src row + dst row.
__global__ void __launch_bounds__(256) edge_kernel(const float* __restrict__ h,
                                                   const int* __restrict__ src,
                                                   const int* __restrict__ dst,
                                                   const float* __restrict__ rnorm,
                                                   float* __restrict__ out,
                                                   int E) {
    int tid = blockIdx.x * blockDim.x + threadIdx.x;
    int e   = tid >> 5;           // 32 lanes per edge
    int sub = threadIdx.x & 31;
    if (e >= E) return;
    int s = src[e];
    int d = dst[e];
    const float4* rs = (const float4*)(h + (size_t)s * 128);
    const float4* rd = (const float4*)(h + (size_t)d * 128);
    float4 a = rs[sub];
    float4 b = rd[sub];
    float p = a.x * b.x + a.y * b.y + a.z * b.z + a.w * b.w;
    // reduce across the 32-lane group (xor offsets < 32 stay inside the group)
    #pragma unroll
    for (int off = 16; off > 0; off >>= 1)
        p += __shfl_xor(p, off, 64);
    if (sub == 0)
        out[e] = p * rnorm[s] * rnorm[d];
}

extern "C" void kernel_launch(void* const* d_in, const int* in_sizes, int n_in,
                              void* d_out, int out_size, void* d_ws, size_t ws_size,
                              hipStream_t stream) {
    const float* h   = (const float*)d_in[0];
    const int*   src = (const int*)d_in[1];
    const int*   dst = (const int*)d_in[2];
    float*       out = (float*)d_out;

    const int N = in_sizes[0] / 128;   // 100000
    const int E = in_sizes[1];         // 640000

    float* rnorm = (float*)d_ws;       // N floats of scratch

    // Kernel 1: 4 rows per 256-thread block
    {
        int rows_per_block = 256 / 64;
        int grid = (N + rows_per_block - 1) / rows_per_block;
        rnorm_kernel<<<grid, 256, 0, stream>>>(h, rnorm, N);
    }
    // Kernel 2: 8 edges per 256-thread block
    {
        int edges_per_block = 256 / 32;
        int grid = (E + edges_per_block - 1) / edges_per_block;
        edge_kernel<<<grid, 256, 0, stream>>>(h, src, dst, rnorm, out, E);
    }
}

// Round 2
// 136.912 us; speedup vs baseline: 1.3304x; 1.3304x over previous
//
#include <hip/hip_runtime.h>
#include <math.h>

#define EPS 1e-12f

__device__ inline unsigned short f32_to_bf16_rn(float f) {
    unsigned int u = __float_as_uint(f);
    u += 0x7fffu + ((u >> 16) & 1u);   // round-to-nearest-even
    return (unsigned short)(u >> 16);
}

// Pass 1: L2-normalize each row and store as packed bf16 (64 uints per row).
// One 64-lane wave per row; lane holds float2 (2 elements of 128).
__global__ void __launch_bounds__(256) norm_bf16_kernel(const float* __restrict__ h,
                                                        unsigned int* __restrict__ hn,
                                                        int N) {
    int row  = (blockIdx.x * blockDim.x + threadIdx.x) >> 6;
    int lane = threadIdx.x & 63;
    if (row >= N) return;
    const float2* rp = (const float2*)(h + (size_t)row * 128);
    float2 v = rp[lane];
    float s = v.x * v.x + v.y * v.y;
    #pragma unroll
    for (int off = 32; off > 0; off >>= 1)
        s += __shfl_xor(s, off, 64);           // all lanes end with full sum
    float r = 1.0f / fmaxf(sqrtf(s), EPS);
    unsigned int lo = f32_to_bf16_rn(v.x * r);
    unsigned int hi = f32_to_bf16_rn(v.y * r);
    hn[(size_t)row * 64 + lane] = lo | (hi << 16);
}

// Pass 2: per-edge dot on normalized bf16 rows. 16 lanes/edge, 16 B/lane.
__device__ inline float dot2_bf16pair(unsigned int u, unsigned int v) {
    float ul = __uint_as_float(u << 16);
    float uh = __uint_as_float(u & 0xffff0000u);
    float vl = __uint_as_float(v << 16);
    float vh = __uint_as_float(v & 0xffff0000u);
    return fmaf(ul, vl, uh * vh);
}

__global__ void __launch_bounds__(256) edge_bf16_kernel(const uint4* __restrict__ hn,
                                                        const int* __restrict__ src,
                                                        const int* __restrict__ dst,
                                                        float* __restrict__ out,
                                                        int E) {
    int tid = blockIdx.x * blockDim.x + threadIdx.x;
    int e   = tid >> 4;            // 16 lanes per edge
    int sub = threadIdx.x & 15;
    if (e >= E) return;
    int s = src[e];
    int d = dst[e];
    uint4 a = hn[(size_t)s * 16 + sub];   // 256 B per row, 16 B per lane
    uint4 b = hn[(size_t)d * 16 + sub];
    float p = dot2_bf16pair(a.x, b.x);
    p += dot2_bf16pair(a.y, b.y);
    p += dot2_bf16pair(a.z, b.z);
    p += dot2_bf16pair(a.w, b.w);
    #pragma unroll
    for (int off = 8; off > 0; off >>= 1)
        p += __shfl_xor(p, off, 64);       // xor < 16 stays within the 16-lane group
    if (sub == 0)
        out[e] = p;
}

// ---- Fallback path (ws too small): round-1 kernels ----
__global__ void __launch_bounds__(256) rnorm_kernel(const float* __restrict__ h,
                                                    float* __restrict__ rnorm,
                                                    int N) {
    int row  = (blockIdx.x * blockDim.x + threadIdx.x) >> 6;
    int lane = threadIdx.x & 63;
    if (row >= N) return;
    const float2* rp = (const float2*)(h + (size_t)row * 128);
    float2 v = rp[lane];
    float s = v.x * v.x + v.y * v.y;
    #pragma unroll
    for (int off = 32; off > 0; off >>= 1)
        s += __shfl_xor(s, off, 64);
    if (lane == 0)
        rnorm[row] = 1.0f / fmaxf(sqrtf(s), EPS);
}

__global__ void __launch_bounds__(256) edge_f32_kernel(const float* __restrict__ h,
                                                       const int* __restrict__ src,
                                                       const int* __restrict__ dst,
                                                       const float* __restrict__ rnorm,
                                                       float* __restrict__ out,
                                                       int E) {
    int tid = blockIdx.x * blockDim.x + threadIdx.x;
    int e   = tid >> 5;
    int sub = threadIdx.x & 31;
    if (e >= E) return;
    int s = src[e];
    int d = dst[e];
    const float4* rs = (const float4*)(h + (size_t)s * 128);
    const float4* rd = (const float4*)(h + (size_t)d * 128);
    float4 a = rs[sub];
    float4 b = rd[sub];
    float p = a.x * b.x + a.y * b.y + a.z * b.z + a.w * b.w;
    #pragma unroll
    for (int off = 16; off > 0; off >>= 1)
        p += __shfl_xor(p, off, 64);
    if (sub == 0)
        out[e] = p * rnorm[s] * rnorm[d];
}

extern "C" void kernel_launch(void* const* d_in, const int* in_sizes, int n_in,
                              void* d_out, int out_size, void* d_ws, size_t ws_size,
                              hipStream_t stream) {
    const float* h   = (const float*)d_in[0];
    const int*   src = (const int*)d_in[1];
    const int*   dst = (const int*)d_in[2];
    float*       out = (float*)d_out;

    const int N = in_sizes[0] / 128;   // 100000
    const int E = in_sizes[1];         // 640000

    size_t hn_bytes = (size_t)N * 128 * 2;   // 25.6 MB of packed bf16

    if (ws_size >= hn_bytes) {
        unsigned int* hn = (unsigned int*)d_ws;
        {
            int grid = (N * 64 + 255) / 256;   // one wave (64 lanes) per row
            norm_bf16_kernel<<<grid, 256, 0, stream>>>(h, hn, N);
        }
        {
            int grid = (E * 16 + 255) / 256;   // 16 lanes per edge
            edge_bf16_kernel<<<grid, 256, 0, stream>>>((const uint4*)hn, src, dst, out, E);
        }
    } else {
        float* rnorm = (float*)d_ws;           // N floats
        {
            int grid = (N * 64 + 255) / 256;
            rnorm_kernel<<<grid, 256, 0, stream>>>(h, rnorm, N);
        }
        {
            int grid = (E * 32 + 255) / 256;
            edge_f32_kernel<<<grid, 256, 0, stream>>>(h, src, dst, rnorm, out, E);
        }
    }
}

// Round 3
// 136.002 us; speedup vs baseline: 1.3393x; 1.0067x over previous
//
#include <hip/hip_runtime.h>
#include <math.h>

#define EPS 1e-12f

__device__ inline unsigned short f32_to_bf16_rn(float f) {
    unsigned int u = __float_as_uint(f);
    u += 0x7fffu + ((u >> 16) & 1u);   // round-to-nearest-even
    return (unsigned short)(u >> 16);
}

// Pass 1: L2-normalize each row and store as packed bf16 (64 uints per row).
// One 64-lane wave per row; lane holds float2 (2 elements of 128).
__global__ void __launch_bounds__(256) norm_bf16_kernel(const float* __restrict__ h,
                                                        unsigned int* __restrict__ hn,
                                                        int N) {
    int row  = (blockIdx.x * blockDim.x + threadIdx.x) >> 6;
    int lane = threadIdx.x & 63;
    if (row >= N) return;
    const float2* rp = (const float2*)(h + (size_t)row * 128);
    float2 v = rp[lane];
    float s = v.x * v.x + v.y * v.y;
    #pragma unroll
    for (int off = 32; off > 0; off >>= 1)
        s += __shfl_xor(s, off, 64);           // all lanes end with full sum
    float r = 1.0f / fmaxf(sqrtf(s), EPS);
    unsigned int lo = f32_to_bf16_rn(v.x * r);
    unsigned int hi = f32_to_bf16_rn(v.y * r);
    hn[(size_t)row * 64 + lane] = lo | (hi << 16);
}

__device__ inline float dot2_bf16pair(unsigned int u, unsigned int v) {
    float ul = __uint_as_float(u << 16);
    float uh = __uint_as_float(u & 0xffff0000u);
    float vl = __uint_as_float(v << 16);
    float vh = __uint_as_float(v & 0xffff0000u);
    return fmaf(ul, vl, uh * vh);
}

__device__ inline float dot8_uint4(uint4 a, uint4 b) {
    float p = dot2_bf16pair(a.x, b.x);
    p += dot2_bf16pair(a.y, b.y);
    p += dot2_bf16pair(a.z, b.z);
    p += dot2_bf16pair(a.w, b.w);
    return p;
}

// Pass 2: per-edge dot on normalized bf16 rows.
// 4 lanes per edge; each lane loads 4 uint4 per row (8 independent 16 B
// gathers in flight per thread before first use -> 4x the MLP of the
// 16-lane version).
__global__ void __launch_bounds__(256) edge_bf16_kernel4(const uint4* __restrict__ hn,
                                                         const int* __restrict__ src,
                                                         const int* __restrict__ dst,
                                                         float* __restrict__ out,
                                                         int E) {
    int tid = blockIdx.x * blockDim.x + threadIdx.x;
    int e   = tid >> 2;            // 4 lanes per edge
    int sub = threadIdx.x & 3;
    if (e >= E) return;
    int s = src[e];
    int d = dst[e];
    const uint4* rs = hn + (size_t)s * 16;   // 256 B per row = 16 uint4
    const uint4* rd = hn + (size_t)d * 16;
    // issue all 8 loads back-to-back
    uint4 a0 = rs[sub];
    uint4 a1 = rs[sub + 4];
    uint4 a2 = rs[sub + 8];
    uint4 a3 = rs[sub + 12];
    uint4 b0 = rd[sub];
    uint4 b1 = rd[sub + 4];
    uint4 b2 = rd[sub + 8];
    uint4 b3 = rd[sub + 12];
    float p = dot8_uint4(a0, b0);
    p += dot8_uint4(a1, b1);
    p += dot8_uint4(a2, b2);
    p += dot8_uint4(a3, b3);
    // reduce across the 4-lane group
    p += __shfl_xor(p, 2, 64);
    p += __shfl_xor(p, 1, 64);
    if (sub == 0)
        out[e] = p;
}

// ---- Fallback path (ws too small): round-1 kernels ----
__global__ void __launch_bounds__(256) rnorm_kernel(const float* __restrict__ h,
                                                    float* __restrict__ rnorm,
                                                    int N) {
    int row  = (blockIdx.x * blockDim.x + threadIdx.x) >> 6;
    int lane = threadIdx.x & 63;
    if (row >= N) return;
    const float2* rp = (const float2*)(h + (size_t)row * 128);
    float2 v = rp[lane];
    float s = v.x * v.x + v.y * v.y;
    #pragma unroll
    for (int off = 32; off > 0; off >>= 1)
        s += __shfl_xor(s, off, 64);
    if (lane == 0)
        rnorm[row] = 1.0f / fmaxf(sqrtf(s), EPS);
}

__global__ void __launch_bounds__(256) edge_f32_kernel(const float* __restrict__ h,
                                                       const int* __restrict__ src,
                                                       const int* __restrict__ dst,
                                                       const float* __restrict__ rnorm,
                                                       float* __restrict__ out,
                                                       int E) {
    int tid = blockIdx.x * blockDim.x + threadIdx.x;
    int e   = tid >> 5;
    int sub = threadIdx.x & 31;
    if (e >= E) return;
    int s = src[e];
    int d = dst[e];
    const float4* rs = (const float4*)(h + (size_t)s * 128);
    const float4* rd = (const float4*)(h + (size_t)d * 128);
    float4 a = rs[sub];
    float4 b = rd[sub];
    float p = a.x * b.x + a.y * b.y + a.z * b.z + a.w * b.w;
    #pragma unroll
    for (int off = 16; off > 0; off >>= 1)
        p += __shfl_xor(p, off, 64);
    if (sub == 0)
        out[e] = p * rnorm[s] * rnorm[d];
}

extern "C" void kernel_launch(void* const* d_in, const int* in_sizes, int n_in,
                              void* d_out, int out_size, void* d_ws, size_t ws_size,
                              hipStream_t stream) {
    const float* h   = (const float*)d_in[0];
    const int*   src = (const int*)d_in[1];
    const int*   dst = (const int*)d_in[2];
    float*       out = (float*)d_out;

    const int N = in_sizes[0] / 128;   // 100000
    const int E = in_sizes[1];         // 640000

    size_t hn_bytes = (size_t)N * 128 * 2;   // 25.6 MB of packed bf16

    if (ws_size >= hn_bytes) {
        unsigned int* hn = (unsigned int*)d_ws;
        {
            int grid = (N * 64 + 255) / 256;   // one wave (64 lanes) per row
            norm_bf16_kernel<<<grid, 256, 0, stream>>>(h, hn, N);
        }
        {
            long long threads = (long long)E * 4;   // 4 lanes per edge
            int grid = (int)((threads + 255) / 256);
            edge_bf16_kernel4<<<grid, 256, 0, stream>>>((const uint4*)hn, src, dst, out, E);
        }
    } else {
        float* rnorm = (float*)d_ws;           // N floats
        {
            int grid = (N * 64 + 255) / 256;
            rnorm_kernel<<<grid, 256, 0, stream>>>(h, rnorm, N);
        }
        {
            int grid = (E * 32 + 255) / 256;
            edge_f32_kernel<<<grid, 256, 0, stream>>>(h, src, dst, rnorm, out, E);
        }
    }
}

// Round 4
// 111.292 us; speedup vs baseline: 1.6367x; 1.2220x over previous
//
#include <hip/hip_runtime.h>
#include <math.h>

#define EPS 1e-12f

// ---------------------------------------------------------------------------
// Pass 1: per-row L2 norm + maxabs; quantize normalized row to int8 with
// per-row scale. 32 lanes per row, each lane owns one float4 (4 of 128).
// Output: hq[row*32 + lane] = 4 packed int8; scale[row] = maxabs_norm/127.
// Note: q = round(127 * x / maxabs_raw) — the 1/||x|| factor cancels, so we
// quantize raw values and fold the norm into the stored scale.
// ---------------------------------------------------------------------------
__global__ void __launch_bounds__(256) norm_q8_kernel(const float* __restrict__ h,
                                                      unsigned int* __restrict__ hq,
                                                      float* __restrict__ scale,
                                                      int N) {
    int tid  = blockIdx.x * blockDim.x + threadIdx.x;
    int row  = tid >> 5;               // 32 lanes per row
    int lane = threadIdx.x & 31;
    if (row >= N) return;
    const float4* rp = (const float4*)(h + (size_t)row * 128);
    float4 v = rp[lane];
    float ss = v.x * v.x + v.y * v.y + v.z * v.z + v.w * v.w;
    float ma = fmaxf(fmaxf(fabsf(v.x), fabsf(v.y)), fmaxf(fabsf(v.z), fabsf(v.w)));
    // xor offsets < 32 stay inside this row's 32-lane group
    #pragma unroll
    for (int off = 16; off > 0; off >>= 1) {
        ss += __shfl_xor(ss, off, 64);
        ma = fmaxf(ma, __shfl_xor(ma, off, 64));
    }
    float r  = 1.0f / fmaxf(sqrtf(ss), EPS);   // 1/||x||
    float qs = 127.0f / fmaxf(ma, 1e-30f);     // quant multiplier on raw x
    int qx = __float2int_rn(v.x * qs);
    int qy = __float2int_rn(v.y * qs);
    int qz = __float2int_rn(v.z * qs);
    int qw = __float2int_rn(v.w * qs);
    unsigned int pack = ((unsigned int)qx & 0xffu)
                      | (((unsigned int)qy & 0xffu) << 8)
                      | (((unsigned int)qz & 0xffu) << 16)
                      | (((unsigned int)qw & 0xffu) << 24);
    hq[(size_t)row * 32 + lane] = pack;
    if (lane == 0)
        scale[row] = ma * r * (1.0f / 127.0f);  // maxabs of NORMALIZED row / 127
}

// int8x4 dot-accumulate
__device__ inline int dot4i8(unsigned int a, unsigned int b, int c) {
#if __has_builtin(__builtin_amdgcn_sdot4)
    return __builtin_amdgcn_sdot4((int)a, (int)b, c, false);
#else
    c += (int)(signed char)(a)       * (int)(signed char)(b);
    c += (int)(signed char)(a >> 8)  * (int)(signed char)(b >> 8);
    c += (int)(signed char)(a >> 16) * (int)(signed char)(b >> 16);
    c += (int)(signed char)(a >> 24) * (int)(signed char)(b >> 24);
    return c;
#endif
}

__device__ inline int dot16(uint4 a, uint4 b, int c) {
    c = dot4i8(a.x, b.x, c);
    c = dot4i8(a.y, b.y, c);
    c = dot4i8(a.z, b.z, c);
    c = dot4i8(a.w, b.w, c);
    return c;
}

// ---------------------------------------------------------------------------
// Pass 2: per-edge dot on int8 rows. 4 lanes/edge; each lane loads 2 uint4
// per row (row = 128 B = 8 uint4). Integer accumulate (max |sum| ~2.1e6,
// fits int32), then out = acc * scale[s] * scale[d].
// ---------------------------------------------------------------------------
__global__ void __launch_bounds__(256) edge_q8_kernel(const uint4* __restrict__ hq,
                                                      const int* __restrict__ src,
                                                      const int* __restrict__ dst,
                                                      const float* __restrict__ scale,
                                                      float* __restrict__ out,
                                                      int E) {
    int tid = blockIdx.x * blockDim.x + threadIdx.x;
    int e   = tid >> 2;               // 4 lanes per edge
    int sub = threadIdx.x & 3;
    if (e >= E) return;
    int s = src[e];
    int d = dst[e];
    const uint4* rs = hq + (size_t)s * 8;
    const uint4* rd = hq + (size_t)d * 8;
    // issue all gathers back-to-back
    uint4 a0 = rs[sub];
    uint4 a1 = rs[sub + 4];
    uint4 b0 = rd[sub];
    uint4 b1 = rd[sub + 4];
    float sa = scale[s];
    float sd = scale[d];
    int acc = 0;
    acc = dot16(a0, b0, acc);
    acc = dot16(a1, b1, acc);
    // reduce across the 4-lane group
    acc += __shfl_xor(acc, 2, 64);
    acc += __shfl_xor(acc, 1, 64);
    if (sub == 0)
        out[e] = (float)acc * sa * sd;
}

// ---- Fallback path (ws too small): round-1 f32 kernels ----
__global__ void __launch_bounds__(256) rnorm_kernel(const float* __restrict__ h,
                                                    float* __restrict__ rnorm,
                                                    int N) {
    int row  = (blockIdx.x * blockDim.x + threadIdx.x) >> 6;
    int lane = threadIdx.x & 63;
    if (row >= N) return;
    const float2* rp = (const float2*)(h + (size_t)row * 128);
    float2 v = rp[lane];
    float s = v.x * v.x + v.y * v.y;
    #pragma unroll
    for (int off = 32; off > 0; off >>= 1)
        s += __shfl_xor(s, off, 64);
    if (lane == 0)
        rnorm[row] = 1.0f / fmaxf(sqrtf(s), EPS);
}

__global__ void __launch_bounds__(256) edge_f32_kernel(const float* __restrict__ h,
                                                       const int* __restrict__ src,
                                                       const int* __restrict__ dst,
                                                       const float* __restrict__ rnorm,
                                                       float* __restrict__ out,
                                                       int E) {
    int tid = blockIdx.x * blockDim.x + threadIdx.x;
    int e   = tid >> 5;
    int sub = threadIdx.x & 31;
    if (e >= E) return;
    int s = src[e];
    int d = dst[e];
    const float4* rs = (const float4*)(h + (size_t)s * 128);
    const float4* rd = (const float4*)(h + (size_t)d * 128);
    float4 a = rs[sub];
    float4 b = rd[sub];
    float p = a.x * b.x + a.y * b.y + a.z * b.z + a.w * b.w;
    #pragma unroll
    for (int off = 16; off > 0; off >>= 1)
        p += __shfl_xor(p, off, 64);
    if (sub == 0)
        out[e] = p * rnorm[s] * rnorm[d];
}

extern "C" void kernel_launch(void* const* d_in, const int* in_sizes, int n_in,
                              void* d_out, int out_size, void* d_ws, size_t ws_size,
                              hipStream_t stream) {
    const float* h   = (const float*)d_in[0];
    const int*   src = (const int*)d_in[1];
    const int*   dst = (const int*)d_in[2];
    float*       out = (float*)d_out;

    const int N = in_sizes[0] / 128;   // 100000
    const int E = in_sizes[1];         // 640000

    size_t hq_bytes    = (size_t)N * 128;        // 12.8 MB int8 rows
    size_t scale_bytes = (size_t)N * sizeof(float);

    if (ws_size >= hq_bytes + scale_bytes) {
        unsigned int* hq    = (unsigned int*)d_ws;
        float*        scale = (float*)((char*)d_ws + hq_bytes);
        {
            long long threads = (long long)N * 32;   // 32 lanes per row
            int grid = (int)((threads + 255) / 256);
            norm_q8_kernel<<<grid, 256, 0, stream>>>(h, hq, scale, N);
        }
        {
            long long threads = (long long)E * 4;    // 4 lanes per edge
            int grid = (int)((threads + 255) / 256);
            edge_q8_kernel<<<grid, 256, 0, stream>>>((const uint4*)hq, src, dst,
                                                     scale, out, E);
        }
    } else {
        float* rnorm = (float*)d_ws;                 // N floats
        {
            int grid = (N * 64 + 255) / 256;
            rnorm_kernel<<<grid, 256, 0, stream>>>(h, rnorm, N);
        }
        {
            int grid = (E * 32 + 255) / 256;
            edge_f32_kernel<<<grid, 256, 0, stream>>>(h, src, dst, rnorm, out, E);
        }
    }
}